// Round 2
// baseline (544.672 us; speedup 1.0000x reference)
//
#include <hip/hip_runtime.h>

#define F1260 1260

__device__ __forceinline__ float leakyf(float x) { return x >= 0.f ? x : 0.2f * x; }
__device__ __forceinline__ float eluf(float x) { return x > 0.f ? x : expm1f(x); }
__device__ __forceinline__ float sigmoidf(float x) { return 1.f / (1.f + __expf(-x)); }

// ws float layout (runtime-selected replica count NR = 8 or 1):
//   stats region: NR replicas of 2560 floats:
//       r*2560 + f        : fsum   (f in [0,1260))
//       r*2560 + 1280 + f : fsq
//   param block at PB = NR*2560:
//       PB+0    scale[42]      PB+64   shift[42]
//       PB+128  adjn[7][49]
//       PB+512  WB[180][24]  (per k=c*30+tt: [0..17]=GAT1 hh*3+{si,sj,we},
//                             [18..20]={a2si,a2sj,W2[tt][0]}, 3 pad)
//       PB+4832 bias[84] (b_ih+b_hh)   PB+4928 Wout[147]   PB+5078 bout[7]
//   total = NR*2560 + 5085 floats  (NR=8: 102.3 KB, NR=1: 30.6 KB)

// ---------------- kA: BN stats, float4-coalesced, 128 rows/block ----------------
// 256 blocks (1/CU). Atomic adds land in replica (blockIdx & (NR-1)) -> chain
// depth per address drops 256 -> 32; replica index aligns with XCD round-robin
// so contenders share an L2.
__global__ __launch_bounds__(320) void kA_stats(const float* __restrict__ x,
                                                float* __restrict__ ws, int nrep) {
    const int t = threadIdx.x;
    if (t >= 315) return;
    const int n0 = blockIdx.x * 128;
    const int f0 = t * 4;
    float* base = ws + (size_t)(blockIdx.x & (nrep - 1)) * 2560;
    float s0 = 0.f, s1 = 0.f, s2 = 0.f, s3 = 0.f;
    float q0 = 0.f, q1 = 0.f, q2 = 0.f, q3 = 0.f;
#pragma unroll 16
    for (int i = 0; i < 128; ++i) {
        const float4 a = *(const float4*)(x + (size_t)(n0 + i) * F1260 + f0);
        s0 += a.x; q0 += a.x * a.x;
        s1 += a.y; q1 += a.y * a.y;
        s2 += a.z; q2 += a.z * a.z;
        s3 += a.w; q3 += a.w * a.w;
    }
    atomicAdd(&base[f0 + 0], s0);
    atomicAdd(&base[f0 + 1], s1);
    atomicAdd(&base[f0 + 2], s2);
    atomicAdd(&base[f0 + 3], s3);
    atomicAdd(&base[1280 + f0 + 0], q0);
    atomicAdd(&base[1280 + f0 + 1], q1);
    atomicAdd(&base[1280 + f0 + 2], q2);
    atomicAdd(&base[1280 + f0 + 3], q3);
}

// ---------------- kB: finalize BN, adjacency norm, weight folds ----------------
__global__ __launch_bounds__(256) void kB_setup(
        const float* __restrict__ bn_gamma, const float* __restrict__ bn_beta,
        const float* __restrict__ W1, const float* __restrict__ a1, const float* __restrict__ B1,
        const float* __restrict__ W2, const float* __restrict__ a2, const float* __restrict__ B2,
        const float* __restrict__ b_ih, const float* __restrict__ b_hh,
        const float* __restrict__ W_out, const float* __restrict__ b_out,
        float* __restrict__ ws, int nrep, int N) {
    const int t = threadIdx.x;
    float* pb = ws + (size_t)nrep * 2560;
    const int HH[6] = {0, 3, 6, 10, 13, 16};
    const int EH[6] = {0, 3, 6, 0, 3, 6};

    // per-channel BN scale/shift; channel ch = v*6 + c; flat f = c*210 + tt*7 + v
    if (t < 42) {
        const int v = t / 6, c = t % 6;
        float s = 0.f, q = 0.f;
        for (int tt = 0; tt < 30; ++tt) {
            const int f = c * 210 + tt * 7 + v;
            for (int r = 0; r < nrep; ++r) {
                s += ws[r * 2560 + f];
                q += ws[r * 2560 + 1280 + f];
            }
        }
        const float cnt = 30.f * (float)N;
        const float mean = s / cnt;
        const float var = q / cnt - mean * mean;
        const float sc = bn_gamma[t] * rsqrtf(var + 1e-5f);
        pb[t] = sc;
        pb[64 + t] = bn_beta[t] - mean * sc;
    }
    // normalized adjacency: 6 GAT1 heads + GAT2 head0
    if (t >= 64 && t < 71) {
        const int idx = t - 64;
        const float* Bp = (idx < 6) ? (B1 + HH[idx] * 49) : B2;
        float* op = pb + 128 + idx * 49;
        float adj[49];
        for (int i = 0; i < 49; ++i) adj[i] = Bp[i];
        for (int i = 0; i < 7; ++i) adj[i * 8] += 1.f;
        float mn = adj[0], mx = adj[0];
        for (int i = 1; i < 49; ++i) { mn = fminf(mn, adj[i]); mx = fmaxf(mx, adj[i]); }
        const float inv = 1.f / (mx - mn);
        float rinv[7];
        for (int i = 0; i < 7; ++i) {
            float rs = 0.f;
            for (int j = 0; j < 7; ++j) { adj[i * 7 + j] = (adj[i * 7 + j] - mn) * inv; rs += adj[i * 7 + j]; }
            rinv[i] = rsqrtf(rs);
        }
        for (int i = 0; i < 7; ++i)
            for (int j = 0; j < 7; ++j)
                op[i * 7 + j] = adj[i * 7 + j] * rinv[i] * rinv[j];
    }
    // WB: fold a1 into W1 for the 6 live heads, repacked per-k
    for (int task = t; task < 6 * 180; task += 256) {
        const int hh = task / 180, k = task % 180;
        const int h = HH[hh];
        const float* Wp = W1 + ((size_t)h * 180 + k) * 9;
        float si = 0.f, sj = 0.f;
        for (int e = 0; e < 9; ++e) {
            const float w = Wp[e];
            si += w * a1[h * 18 + e];
            sj += w * a1[h * 18 + 9 + e];
        }
        pb[512 + k * 24 + hh * 3 + 0] = si;
        pb[512 + k * 24 + hh * 3 + 1] = sj;
        pb[512 + k * 24 + hh * 3 + 2] = Wp[EH[hh]];
    }
    // WA2 slots (replicated per c): head 0 of l2, f=0 column kept
    if (t < 30) {
        const float* Wp = W2 + t * 10;
        float si = 0.f, sj = 0.f;
        for (int f = 0; f < 10; ++f) {
            const float w = Wp[f];
            si += w * a2[f];
            sj += w * a2[10 + f];
        }
        for (int c = 0; c < 6; ++c) {
            const int k = c * 30 + t;
            pb[512 + k * 24 + 18] = si;
            pb[512 + k * 24 + 19] = sj;
            pb[512 + k * 24 + 20] = Wp[0];
        }
    }
    if (t < 84) pb[4832 + t] = b_ih[t] + b_hh[t];
    if (t < 147) pb[4928 + t] = W_out[t];
    if (t < 7) pb[5078 + t] = b_out[t];
}

// ---------------- kC: fused dots + attention + LSTM + out ----------------
// Single-wave blocks (64 threads, 8 samples). Phase-1 gathers x directly with a
// REGISTER DOUBLE BUFFER: chunk c+1's 30 loads issue before chunk c's 660 FMAs,
// hiding ~600-cycle L3/HBM latency under compute. __launch_bounds__(64,3) pins
// VGPR <= 170 so occupancy stays 3 waves/SIMD (LDS 14.7 KB -> 11 blocks/CU).
#define RS 253          // res row stride (floats); 252 used
// LDS float map: res [8][253] @0, xs0 [8][88] @2024 (rows 16B-aligned),
//   h2t [8][42] @2728, h1s [8][22] @3064, scsh [84] @3240, adjL [343] @3324
//   -> 3667 floats = 14668 B
__global__ __launch_bounds__(64, 3) void kC_main(const float* __restrict__ x,
        const float* __restrict__ pb, const float* __restrict__ Wih,
        float* __restrict__ outp, int N) {
    __shared__ __align__(16) float sm[3667];
    float* res  = sm;
    float* xs0  = sm + 2024;
    float* h2t  = sm + 2728;
    float* h1s  = sm + 3064;
    float* scsh = sm + 3240;
    float* adjL = sm + 3324;

    const int t = threadIdx.x;
    const int n0 = blockIdx.x * 8;
    const int v = t >> 3, nl = t & 7;

    const float* xb = x + (size_t)(n0 + nl) * F1260 + v;
    float xva[30], xvb[30];

#define LOADCH(dst, cc)                                               \
    {                                                                 \
        const float* xr_ = xb + (cc) * 210;                           \
        _Pragma("unroll")                                             \
        for (int tt = 0; tt < 30; ++tt) dst[tt] = xr_[tt * 7];        \
    }

    // issue chunk-0 loads first so their latency overlaps param staging
    if (v < 7) LOADCH(xva, 0)

    // ---- phase 0: params ----
    for (int i = t; i < 84; i += 64) scsh[i] = pb[i < 42 ? i : 22 + i];
    for (int i = t; i < 343; i += 64) adjL[i] = pb[128 + i];
    __syncthreads();

    // ---- phase 1: dots; thread = (v, nl), 56 active; 6-step pipelined ----
    float s1[18];
#pragma unroll
    for (int i = 0; i < 18; ++i) s1[i] = 0.f;

#define COMPCH(cur, cc)                                               \
    {                                                                 \
        const float sc = scsh[v * 6 + (cc)];                          \
        const float sh = scsh[42 + v * 6 + (cc)];                     \
        const float* wb_ = pb + 512 + ((cc) * 30) * 24;               \
        float g0 = 0.f, g1 = 0.f, g2 = 0.f;                           \
        _Pragma("unroll")                                             \
        for (int tt = 0; tt < 30; ++tt) {                             \
            const float a = cur[tt] * sc + sh;                        \
            const float* w = wb_ + tt * 24;                           \
            _Pragma("unroll")                                         \
            for (int q = 0; q < 18; ++q) s1[q] += a * w[q];           \
            g0 += a * w[18];                                          \
            g1 += a * w[19];                                          \
            g2 += a * w[20];                                          \
        }                                                             \
        float* rp_ = res + nl * RS + 126 + (v * 6 + (cc)) * 3;        \
        rp_[0] = g0; rp_[1] = g1; rp_[2] = g2;                        \
    }

    if (v < 7) {
        LOADCH(xvb, 1) COMPCH(xva, 0)
        LOADCH(xva, 2) COMPCH(xvb, 1)
        LOADCH(xvb, 3) COMPCH(xva, 2)
        LOADCH(xva, 4) COMPCH(xvb, 3)
        LOADCH(xvb, 5) COMPCH(xva, 4)
                       COMPCH(xvb, 5)
#pragma unroll
        for (int q = 0; q < 18; ++q)
            res[nl * RS + v * 18 + q] = s1[q];
    }
    __syncthreads();

    // ---- phase 2: GAT1 heads; thread = (hh, nl), 48 active ----
    if (t < 48) {
        const int hh = t >> 3, nl2 = t & 7;
        float si[7], sj[7], we[7];
#pragma unroll
        for (int vv = 0; vv < 7; ++vv) {
            const float* rp = res + nl2 * RS + vv * 18 + hh * 3;
            si[vv] = rp[0]; sj[vv] = rp[1]; we[vv] = rp[2];
        }
        float mxsj = sj[0];
#pragma unroll
        for (int j = 1; j < 7; ++j) mxsj = fmaxf(mxsj, sj[j]);
        float p[7];
#pragma unroll
        for (int i = 0; i < 7; ++i) {
            const float m = leakyf(si[i] + mxsj);   // leaky monotonic -> row max
            float den = 0.f, num = 0.f;
#pragma unroll
            for (int j = 0; j < 7; ++j) {
                const float w = __expf(leakyf(si[i] + sj[j]) - m);
                den += w;
                num += w * we[j];
            }
            p[i] = num / den;
        }
        const float* An = adjL + hh * 49;
#pragma unroll
        for (int i = 0; i < 7; ++i) {
            float r = 0.f;
#pragma unroll
            for (int k = 0; k < 7; ++k) r += An[i * 7 + k] * p[k];
            xs0[nl2 * 88 + hh * 7 + i] = eluf(r);
        }
    }
    // ---- phase 2b: GAT2 softmax-over-channels; thread = (i, nl), 56 active ----
    if (t < 56) {
        const int i = t >> 3, nl2 = t & 7;
        float si2[6];
#pragma unroll
        for (int c = 0; c < 6; ++c)
            si2[c] = res[nl2 * RS + 126 + (i * 6 + c) * 3];
        float hc[6];
#pragma unroll
        for (int c = 0; c < 6; ++c) hc[c] = 0.f;
#pragma unroll
        for (int j = 0; j < 7; ++j) {
            float s[6];
            float m = -1e30f;
#pragma unroll
            for (int c = 0; c < 6; ++c) {
                const float* rp = res + nl2 * RS + 126 + (j * 6 + c) * 3;
                s[c] = leakyf(si2[c] + rp[1]);
                m = fmaxf(m, s[c]);
            }
            float den = 0.f;
#pragma unroll
            for (int c = 0; c < 6; ++c) { s[c] = __expf(s[c] - m); den += s[c]; }
            const float rd = 1.f / den;
#pragma unroll
            for (int c = 0; c < 6; ++c) {
                const float wh0 = res[nl2 * RS + 126 + (j * 6 + c) * 3 + 2];
                hc[c] += wh0 * s[c] * rd;
            }
        }
#pragma unroll
        for (int c = 0; c < 6; ++c)
            h2t[nl2 * 42 + i * 6 + c] = hc[c];
    }
    __syncthreads();

    // ---- phase 3: GAT2 adj multiply; thread = (c, nl), 48 active ----
    if (t < 48) {
        const int c = t >> 3, nl2 = t & 7;
        const float* An2 = adjL + 6 * 49;
        float h[7];
#pragma unroll
        for (int u = 0; u < 7; ++u) h[u] = h2t[nl2 * 42 + u * 6 + c];
#pragma unroll
        for (int vv = 0; vv < 7; ++vv) {
            float r = 0.f;
#pragma unroll
            for (int u = 0; u < 7; ++u) r += h[u] * An2[u * 7 + vv];
            xs0[nl2 * 88 + 42 + c * 7 + vv] = eluf(r);
        }
    }
    __syncthreads();

    // ---- phase 4: LSTM step 0; thread = (g8, nl), all 64; float4 reads ----
    {
        const int g8 = t >> 3, nl2 = t & 7;
        const float* bias = pb + 4832;
        const float4* xs4 = (const float4*)(xs0 + nl2 * 88);
        for (int gi = g8; gi < 21; gi += 8) {
            float ga = bias[gi], gg = bias[42 + gi], go = bias[63 + gi];
            const float4* wa = (const float4*)(Wih + gi * 84);
            const float4* wg = (const float4*)(Wih + (42 + gi) * 84);
            const float4* wo = (const float4*)(Wih + (63 + gi) * 84);
#pragma unroll
            for (int k = 0; k < 21; ++k) {
                const float4 xv = xs4[k];
                const float4 a4 = wa[k];
                const float4 g4 = wg[k];
                const float4 o4 = wo[k];
                ga += xv.x * a4.x + xv.y * a4.y + xv.z * a4.z + xv.w * a4.w;
                gg += xv.x * g4.x + xv.y * g4.y + xv.z * g4.z + xv.w * g4.w;
                go += xv.x * o4.x + xv.y * o4.y + xv.z * o4.z + xv.w * o4.w;
            }
            const float c1 = sigmoidf(ga) * tanhf(gg);
            h1s[nl2 * 22 + gi] = sigmoidf(go) * tanhf(c1);
        }
    }
    __syncthreads();

    // ---- phase 5: output projection; thread = nl*7+j, 56 active, coalesced ----
    if (t < 56) {
        const int nl2 = t / 7, j = t - nl2 * 7;
        const float* Wout = pb + 4928;
        float r = pb[5078 + j];
#pragma unroll
        for (int m = 0; m < 21; ++m) r += h1s[nl2 * 22 + m] * Wout[j * 21 + m];
        outp[(size_t)n0 * 7 + t] = r;
    }
}

extern "C" void kernel_launch(void* const* d_in, const int* in_sizes, int n_in,
                              void* d_out, int out_size, void* d_ws, size_t ws_size,
                              hipStream_t stream) {
    const int N = in_sizes[0] / F1260;

    const float* x        = (const float*)d_in[0];
    const float* bn_gamma = (const float*)d_in[1];
    const float* bn_beta  = (const float*)d_in[2];
    const float* W1       = (const float*)d_in[3];
    const float* a1       = (const float*)d_in[4];
    const float* B1       = (const float*)d_in[5];
    const float* W2       = (const float*)d_in[6];
    const float* a2       = (const float*)d_in[7];
    const float* B2       = (const float*)d_in[8];
    const float* W_ih     = (const float*)d_in[9];
    // d_in[10] = W_hh unused (h0 = 0 -> only LSTM step 0 matters)
    const float* b_ih     = (const float*)d_in[11];
    const float* b_hh     = (const float*)d_in[12];
    const float* W_out    = (const float*)d_in[13];
    const float* b_out    = (const float*)d_in[14];

    float* wsf = (float*)d_ws;

    // 8 stat replicas if the workspace allows (102.3 KB), else 1 (30.6 KB)
    const int nrep = (ws_size >= (size_t)(8 * 2560 + 5085 + 256) * sizeof(float)) ? 8 : 1;

    hipMemsetAsync(d_ws, 0, (size_t)nrep * 2560 * sizeof(float), stream);

    kA_stats<<<dim3(N / 128), dim3(320), 0, stream>>>(x, wsf, nrep);
    kB_setup<<<dim3(1), dim3(256), 0, stream>>>(bn_gamma, bn_beta, W1, a1, B1,
                                                W2, a2, B2, b_ih, b_hh,
                                                W_out, b_out, wsf, nrep, N);
    kC_main<<<dim3(N / 8), dim3(64), 0, stream>>>(x, wsf + (size_t)nrep * 2560,
                                                  W_ih, (float*)d_out, N);
}

// Round 3
// 499.095 us; speedup vs baseline: 1.0913x; 1.0913x over previous
//
#include <hip/hip_runtime.h>

#define F1260 1260

__device__ __forceinline__ float leakyf(float x) { return x >= 0.f ? x : 0.2f * x; }
__device__ __forceinline__ float eluf(float x) { return x > 0.f ? x : expm1f(x); }
__device__ __forceinline__ float sigmoidf(float x) { return 1.f / (1.f + __expf(-x)); }

// ws float layout (runtime-selected replica count NR = 8 or 1):
//   stats region: NR replicas of 2560 floats:
//       r*2560 + f        : fsum   (f in [0,1260))
//       r*2560 + 1280 + f : fsq
//   param block at PB = NR*2560:
//       PB+0    scale[42]      PB+64   shift[42]
//       PB+128  adjn[7][49]
//       PB+512  WB[180][24]  (per k=c*30+tt: [0..17]=GAT1 hh*3+{si,sj,we},
//                             [18..20]={a2si,a2sj,W2[tt][0]}, 3 pad)
//       PB+4832 bias[84] (b_ih+b_hh)   PB+4928 Wout[147]   PB+5078 bout[7]
//   total = NR*2560 + 5085 floats  (NR=8: 102.3 KB, NR=1: 30.6 KB)

// ---------------- kA: BN stats, float4-coalesced, 128 rows/block ----------------
// 256 blocks (1/CU). Atomic adds land in replica (blockIdx & (NR-1)) -> chain
// depth per address 32.
__global__ __launch_bounds__(320) void kA_stats(const float* __restrict__ x,
                                                float* __restrict__ ws, int nrep) {
    const int t = threadIdx.x;
    if (t >= 315) return;
    const int n0 = blockIdx.x * 128;
    const int f0 = t * 4;
    float* base = ws + (size_t)(blockIdx.x & (nrep - 1)) * 2560;
    float s0 = 0.f, s1 = 0.f, s2 = 0.f, s3 = 0.f;
    float q0 = 0.f, q1 = 0.f, q2 = 0.f, q3 = 0.f;
#pragma unroll 8
    for (int i = 0; i < 128; ++i) {
        const float4 a = *(const float4*)(x + (size_t)(n0 + i) * F1260 + f0);
        s0 += a.x; q0 += a.x * a.x;
        s1 += a.y; q1 += a.y * a.y;
        s2 += a.z; q2 += a.z * a.z;
        s3 += a.w; q3 += a.w * a.w;
    }
    atomicAdd(&base[f0 + 0], s0);
    atomicAdd(&base[f0 + 1], s1);
    atomicAdd(&base[f0 + 2], s2);
    atomicAdd(&base[f0 + 3], s3);
    atomicAdd(&base[1280 + f0 + 0], q0);
    atomicAdd(&base[1280 + f0 + 1], q1);
    atomicAdd(&base[1280 + f0 + 2], q2);
    atomicAdd(&base[1280 + f0 + 3], q3);
}

// ---------------- kB: finalize BN, adjacency norm, weight folds ----------------
__global__ __launch_bounds__(256) void kB_setup(
        const float* __restrict__ bn_gamma, const float* __restrict__ bn_beta,
        const float* __restrict__ W1, const float* __restrict__ a1, const float* __restrict__ B1,
        const float* __restrict__ W2, const float* __restrict__ a2, const float* __restrict__ B2,
        const float* __restrict__ b_ih, const float* __restrict__ b_hh,
        const float* __restrict__ W_out, const float* __restrict__ b_out,
        float* __restrict__ ws, int nrep, int N) {
    const int t = threadIdx.x;
    float* pb = ws + (size_t)nrep * 2560;
    const int HH[6] = {0, 3, 6, 10, 13, 16};
    const int EH[6] = {0, 3, 6, 0, 3, 6};

    // per-channel BN scale/shift; channel ch = v*6 + c; flat f = c*210 + tt*7 + v
    if (t < 42) {
        const int v = t / 6, c = t % 6;
        float s = 0.f, q = 0.f;
        for (int tt = 0; tt < 30; ++tt) {
            const int f = c * 210 + tt * 7 + v;
            for (int r = 0; r < nrep; ++r) {
                s += ws[r * 2560 + f];
                q += ws[r * 2560 + 1280 + f];
            }
        }
        const float cnt = 30.f * (float)N;
        const float mean = s / cnt;
        const float var = q / cnt - mean * mean;
        const float sc = bn_gamma[t] * rsqrtf(var + 1e-5f);
        pb[t] = sc;
        pb[64 + t] = bn_beta[t] - mean * sc;
    }
    // normalized adjacency: 6 GAT1 heads + GAT2 head0
    if (t >= 64 && t < 71) {
        const int idx = t - 64;
        const float* Bp = (idx < 6) ? (B1 + HH[idx] * 49) : B2;
        float* op = pb + 128 + idx * 49;
        float adj[49];
        for (int i = 0; i < 49; ++i) adj[i] = Bp[i];
        for (int i = 0; i < 7; ++i) adj[i * 8] += 1.f;
        float mn = adj[0], mx = adj[0];
        for (int i = 1; i < 49; ++i) { mn = fminf(mn, adj[i]); mx = fmaxf(mx, adj[i]); }
        const float inv = 1.f / (mx - mn);
        float rinv[7];
        for (int i = 0; i < 7; ++i) {
            float rs = 0.f;
            for (int j = 0; j < 7; ++j) { adj[i * 7 + j] = (adj[i * 7 + j] - mn) * inv; rs += adj[i * 7 + j]; }
            rinv[i] = rsqrtf(rs);
        }
        for (int i = 0; i < 7; ++i)
            for (int j = 0; j < 7; ++j)
                op[i * 7 + j] = adj[i * 7 + j] * rinv[i] * rinv[j];
    }
    // WB: fold a1 into W1 for the 6 live heads, repacked per-k
    for (int task = t; task < 6 * 180; task += 256) {
        const int hh = task / 180, k = task % 180;
        const int h = HH[hh];
        const float* Wp = W1 + ((size_t)h * 180 + k) * 9;
        float si = 0.f, sj = 0.f;
        for (int e = 0; e < 9; ++e) {
            const float w = Wp[e];
            si += w * a1[h * 18 + e];
            sj += w * a1[h * 18 + 9 + e];
        }
        pb[512 + k * 24 + hh * 3 + 0] = si;
        pb[512 + k * 24 + hh * 3 + 1] = sj;
        pb[512 + k * 24 + hh * 3 + 2] = Wp[EH[hh]];
    }
    // WA2 slots (replicated per c): head 0 of l2, f=0 column kept
    if (t < 30) {
        const float* Wp = W2 + t * 10;
        float si = 0.f, sj = 0.f;
        for (int f = 0; f < 10; ++f) {
            const float w = Wp[f];
            si += w * a2[f];
            sj += w * a2[10 + f];
        }
        for (int c = 0; c < 6; ++c) {
            const int k = c * 30 + t;
            pb[512 + k * 24 + 18] = si;
            pb[512 + k * 24 + 19] = sj;
            pb[512 + k * 24 + 20] = Wp[0];
        }
    }
    if (t < 84) pb[4832 + t] = b_ih[t] + b_hh[t];
    if (t < 147) pb[4928 + t] = W_out[t];
    if (t < 7) pb[5078 + t] = b_out[t];
}

// ---------------- kC: fused dots + attention + LSTM + out ----------------
// Single-wave blocks (64 threads, 8 samples). Phase-1 gathers x directly with a
// HALF-CHUNK register double buffer: 12 halves of 15 values; half h+1's loads
// issue before half h's 315 FMAs (~630 cyc covers ~600 cyc L3 latency).
// Buffers cost only 2x15 VGPR -> no spill, NO min-wave launch-bounds pin
// (round-2 lesson: the (64,3) pin forced 84 VGPR and spilled both buffers,
// +450 MB/dispatch scratch traffic). LDS 14.7 KB -> 11 blocks/CU.
#define RS 253          // res row stride (floats); 252 used
// LDS float map: res [8][253] @0, xs0 [8][88] @2024 (rows 16B-aligned),
//   h2t [8][42] @2728, h1s [8][22] @3064, scsh [84] @3240, adjL [343] @3324
//   -> 3667 floats = 14668 B
__global__ __launch_bounds__(64) void kC_main(const float* __restrict__ x,
        const float* __restrict__ pb, const float* __restrict__ Wih,
        float* __restrict__ outp, int N) {
    __shared__ __align__(16) float sm[3667];
    float* res  = sm;
    float* xs0  = sm + 2024;
    float* h2t  = sm + 2728;
    float* h1s  = sm + 3064;
    float* scsh = sm + 3240;
    float* adjL = sm + 3324;

    const int t = threadIdx.x;
    const int n0 = blockIdx.x * 8;
    const int v = t >> 3, nl = t & 7;

    const float* xb = x + (size_t)(n0 + nl) * F1260 + v;
    float xva[15], xvb[15];

    // half index hh in [0,12): chunk c = hh>>1, byte offset = hh*105 floats
#define LOADH(dst, hh)                                                \
    {                                                                 \
        const float* xr_ = xb + (hh) * 105;                           \
        _Pragma("unroll")                                             \
        for (int tt = 0; tt < 15; ++tt) dst[tt] = xr_[tt * 7];        \
    }

    // issue half-0 loads first so their latency overlaps param staging
    if (v < 7) LOADH(xva, 0)

    // ---- phase 0: params ----
    for (int i = t; i < 84; i += 64) scsh[i] = pb[i < 42 ? i : 22 + i];
    for (int i = t; i < 343; i += 64) adjL[i] = pb[128 + i];
    __syncthreads();

    // ---- phase 1: dots; thread = (v, nl), 56 active; 12-step pipelined ----
    float s1[18];
#pragma unroll
    for (int i = 0; i < 18; ++i) s1[i] = 0.f;
    float g0, g1, g2;

#define COMPH(buf, hh, FIRST, LAST)                                   \
    {                                                                 \
        const int c_ = (hh) >> 1;                                     \
        const float sc = scsh[v * 6 + c_];                            \
        const float sh = scsh[42 + v * 6 + c_];                       \
        const float* wb_ = pb + 512 + (c_ * 30 + ((hh) & 1) * 15) * 24; \
        if (FIRST) { g0 = 0.f; g1 = 0.f; g2 = 0.f; }                  \
        _Pragma("unroll")                                             \
        for (int tt = 0; tt < 15; ++tt) {                             \
            const float a = buf[tt] * sc + sh;                        \
            const float* w = wb_ + tt * 24;                           \
            _Pragma("unroll")                                         \
            for (int q = 0; q < 18; ++q) s1[q] += a * w[q];           \
            g0 += a * w[18];                                          \
            g1 += a * w[19];                                          \
            g2 += a * w[20];                                          \
        }                                                             \
        if (LAST) {                                                   \
            float* rp_ = res + nl * RS + 126 + (v * 6 + c_) * 3;      \
            rp_[0] = g0; rp_[1] = g1; rp_[2] = g2;                    \
        }                                                             \
    }

    if (v < 7) {
        LOADH(xvb, 1)  COMPH(xva, 0, 1, 0)
        LOADH(xva, 2)  COMPH(xvb, 1, 0, 1)
        LOADH(xvb, 3)  COMPH(xva, 2, 1, 0)
        LOADH(xva, 4)  COMPH(xvb, 3, 0, 1)
        LOADH(xvb, 5)  COMPH(xva, 4, 1, 0)
        LOADH(xva, 6)  COMPH(xvb, 5, 0, 1)
        LOADH(xvb, 7)  COMPH(xva, 6, 1, 0)
        LOADH(xva, 8)  COMPH(xvb, 7, 0, 1)
        LOADH(xvb, 9)  COMPH(xva, 8, 1, 0)
        LOADH(xva, 10) COMPH(xvb, 9, 0, 1)
        LOADH(xvb, 11) COMPH(xva, 10, 1, 0)
                       COMPH(xvb, 11, 0, 1)
#pragma unroll
        for (int q = 0; q < 18; ++q)
            res[nl * RS + v * 18 + q] = s1[q];
    }
    __syncthreads();

    // ---- phase 2: GAT1 heads; thread = (hh, nl), 48 active ----
    if (t < 48) {
        const int hh = t >> 3, nl2 = t & 7;
        float si[7], sj[7], we[7];
#pragma unroll
        for (int vv = 0; vv < 7; ++vv) {
            const float* rp = res + nl2 * RS + vv * 18 + hh * 3;
            si[vv] = rp[0]; sj[vv] = rp[1]; we[vv] = rp[2];
        }
        float mxsj = sj[0];
#pragma unroll
        for (int j = 1; j < 7; ++j) mxsj = fmaxf(mxsj, sj[j]);
        float p[7];
#pragma unroll
        for (int i = 0; i < 7; ++i) {
            const float m = leakyf(si[i] + mxsj);   // leaky monotonic -> row max
            float den = 0.f, num = 0.f;
#pragma unroll
            for (int j = 0; j < 7; ++j) {
                const float w = __expf(leakyf(si[i] + sj[j]) - m);
                den += w;
                num += w * we[j];
            }
            p[i] = num / den;
        }
        const float* An = adjL + hh * 49;
#pragma unroll
        for (int i = 0; i < 7; ++i) {
            float r = 0.f;
#pragma unroll
            for (int k = 0; k < 7; ++k) r += An[i * 7 + k] * p[k];
            xs0[nl2 * 88 + hh * 7 + i] = eluf(r);
        }
    }
    // ---- phase 2b: GAT2 softmax-over-channels; thread = (i, nl), 56 active ----
    if (t < 56) {
        const int i = t >> 3, nl2 = t & 7;
        float si2[6];
#pragma unroll
        for (int c = 0; c < 6; ++c)
            si2[c] = res[nl2 * RS + 126 + (i * 6 + c) * 3];
        float hc[6];
#pragma unroll
        for (int c = 0; c < 6; ++c) hc[c] = 0.f;
#pragma unroll
        for (int j = 0; j < 7; ++j) {
            float s[6];
            float m = -1e30f;
#pragma unroll
            for (int c = 0; c < 6; ++c) {
                const float* rp = res + nl2 * RS + 126 + (j * 6 + c) * 3;
                s[c] = leakyf(si2[c] + rp[1]);
                m = fmaxf(m, s[c]);
            }
            float den = 0.f;
#pragma unroll
            for (int c = 0; c < 6; ++c) { s[c] = __expf(s[c] - m); den += s[c]; }
            const float rd = 1.f / den;
#pragma unroll
            for (int c = 0; c < 6; ++c) {
                const float wh0 = res[nl2 * RS + 126 + (j * 6 + c) * 3 + 2];
                hc[c] += wh0 * s[c] * rd;
            }
        }
#pragma unroll
        for (int c = 0; c < 6; ++c)
            h2t[nl2 * 42 + i * 6 + c] = hc[c];
    }
    __syncthreads();

    // ---- phase 3: GAT2 adj multiply; thread = (c, nl), 48 active ----
    if (t < 48) {
        const int c = t >> 3, nl2 = t & 7;
        const float* An2 = adjL + 6 * 49;
        float h[7];
#pragma unroll
        for (int u = 0; u < 7; ++u) h[u] = h2t[nl2 * 42 + u * 6 + c];
#pragma unroll
        for (int vv = 0; vv < 7; ++vv) {
            float r = 0.f;
#pragma unroll
            for (int u = 0; u < 7; ++u) r += h[u] * An2[u * 7 + vv];
            xs0[nl2 * 88 + 42 + c * 7 + vv] = eluf(r);
        }
    }
    __syncthreads();

    // ---- phase 4: LSTM step 0; thread = (g8, nl), all 64; float4 reads ----
    {
        const int g8 = t >> 3, nl2 = t & 7;
        const float* bias = pb + 4832;
        const float4* xs4 = (const float4*)(xs0 + nl2 * 88);
        for (int gi = g8; gi < 21; gi += 8) {
            float ga = bias[gi], gg = bias[42 + gi], go = bias[63 + gi];
            const float4* wa = (const float4*)(Wih + gi * 84);
            const float4* wg = (const float4*)(Wih + (42 + gi) * 84);
            const float4* wo = (const float4*)(Wih + (63 + gi) * 84);
#pragma unroll
            for (int k = 0; k < 21; ++k) {
                const float4 xv = xs4[k];
                const float4 a4 = wa[k];
                const float4 g4 = wg[k];
                const float4 o4 = wo[k];
                ga += xv.x * a4.x + xv.y * a4.y + xv.z * a4.z + xv.w * a4.w;
                gg += xv.x * g4.x + xv.y * g4.y + xv.z * g4.z + xv.w * g4.w;
                go += xv.x * o4.x + xv.y * o4.y + xv.z * o4.z + xv.w * o4.w;
            }
            const float c1 = sigmoidf(ga) * tanhf(gg);
            h1s[nl2 * 22 + gi] = sigmoidf(go) * tanhf(c1);
        }
    }
    __syncthreads();

    // ---- phase 5: output projection; thread = nl*7+j, 56 active, coalesced ----
    if (t < 56) {
        const int nl2 = t / 7, j = t - nl2 * 7;
        const float* Wout = pb + 4928;
        float r = pb[5078 + j];
#pragma unroll
        for (int m = 0; m < 21; ++m) r += h1s[nl2 * 22 + m] * Wout[j * 21 + m];
        outp[(size_t)n0 * 7 + t] = r;
    }
}

extern "C" void kernel_launch(void* const* d_in, const int* in_sizes, int n_in,
                              void* d_out, int out_size, void* d_ws, size_t ws_size,
                              hipStream_t stream) {
    const int N = in_sizes[0] / F1260;

    const float* x        = (const float*)d_in[0];
    const float* bn_gamma = (const float*)d_in[1];
    const float* bn_beta  = (const float*)d_in[2];
    const float* W1       = (const float*)d_in[3];
    const float* a1       = (const float*)d_in[4];
    const float* B1       = (const float*)d_in[5];
    const float* W2       = (const float*)d_in[6];
    const float* a2       = (const float*)d_in[7];
    const float* B2       = (const float*)d_in[8];
    const float* W_ih     = (const float*)d_in[9];
    // d_in[10] = W_hh unused (h0 = 0 -> only LSTM step 0 matters)
    const float* b_ih     = (const float*)d_in[11];
    const float* b_hh     = (const float*)d_in[12];
    const float* W_out    = (const float*)d_in[13];
    const float* b_out    = (const float*)d_in[14];

    float* wsf = (float*)d_ws;

    // 8 stat replicas if the workspace allows (102.3 KB), else 1 (30.6 KB)
    const int nrep = (ws_size >= (size_t)(8 * 2560 + 5085 + 256) * sizeof(float)) ? 8 : 1;

    hipMemsetAsync(d_ws, 0, (size_t)nrep * 2560 * sizeof(float), stream);

    kA_stats<<<dim3(N / 128), dim3(320), 0, stream>>>(x, wsf, nrep);
    kB_setup<<<dim3(1), dim3(256), 0, stream>>>(bn_gamma, bn_beta, W1, a1, B1,
                                                W2, a2, B2, b_ih, b_hh,
                                                W_out, b_out, wsf, nrep, N);
    kC_main<<<dim3(N / 8), dim3(64), 0, stream>>>(x, wsf + (size_t)nrep * 2560,
                                                  W_ih, (float*)d_out, N);
}

// Round 4
// 390.503 us; speedup vs baseline: 1.3948x; 1.2781x over previous
//
#include <hip/hip_runtime.h>

#define F1260 1260

__device__ __forceinline__ float leakyf(float x) { return x >= 0.f ? x : 0.2f * x; }
__device__ __forceinline__ float eluf(float x) { return x > 0.f ? x : expm1f(x); }
__device__ __forceinline__ float sigmoidf(float x) { return 1.f / (1.f + __expf(-x)); }
// fast tanh: exact saturation (exp->inf => 1, exp->0 => -1), ~1e-6 abs err
__device__ __forceinline__ float tanh_fast(float x) { return 1.f - 2.f / (__expf(2.f * x) + 1.f); }

// ws float layout:
//   0..1259   : fsum per flat-feature f      (atomic accum, memset to 0)
//   1280..2539: fsq per flat-feature f
//   param block pb = ws + 2560:
//       pb+0    scale[42]      pb+64   shift[42]
//       pb+128  adjn[7][49]
//       pb+512  WB[180][24]  (per k=c*30+tt: [0..17]=GAT1 hh*3+{si,sj,we},
//                             [18..20]={a2si,a2sj,W2[tt][0]}, 3 pad)
//       pb+4832 bias[84] (b_ih+b_hh)   pb+4928 Wout[147]   pb+5078 bout[7]
//   total = 7645 floats (30.6 KB)

// ---------------- kA: BN stats, float4-coalesced, 128 rows/block ----------------
// r1-exact: 256 blocks (1/CU), depth-256 atomics over 2520 distinct addresses
// (replica variants measured neutral-to-worse in r2/r3).
__global__ __launch_bounds__(320) void kA_stats(const float* __restrict__ x,
                                                float* __restrict__ ws, int N) {
    const int t = threadIdx.x;
    if (t >= 315) return;
    const int n0 = blockIdx.x * 128;
    const int f0 = t * 4;
    float s0 = 0.f, s1 = 0.f, s2 = 0.f, s3 = 0.f;
    float q0 = 0.f, q1 = 0.f, q2 = 0.f, q3 = 0.f;
#pragma unroll 8
    for (int i = 0; i < 128; ++i) {
        const float4 a = *(const float4*)(x + (size_t)(n0 + i) * F1260 + f0);
        s0 += a.x; q0 += a.x * a.x;
        s1 += a.y; q1 += a.y * a.y;
        s2 += a.z; q2 += a.z * a.z;
        s3 += a.w; q3 += a.w * a.w;
    }
    atomicAdd(&ws[f0 + 0], s0);
    atomicAdd(&ws[f0 + 1], s1);
    atomicAdd(&ws[f0 + 2], s2);
    atomicAdd(&ws[f0 + 3], s3);
    atomicAdd(&ws[1280 + f0 + 0], q0);
    atomicAdd(&ws[1280 + f0 + 1], q1);
    atomicAdd(&ws[1280 + f0 + 2], q2);
    atomicAdd(&ws[1280 + f0 + 3], q3);
}

// ---------------- kB: finalize BN, adjacency norm, weight folds ----------------
__global__ __launch_bounds__(256) void kB_setup(
        const float* __restrict__ bn_gamma, const float* __restrict__ bn_beta,
        const float* __restrict__ W1, const float* __restrict__ a1, const float* __restrict__ B1,
        const float* __restrict__ W2, const float* __restrict__ a2, const float* __restrict__ B2,
        const float* __restrict__ b_ih, const float* __restrict__ b_hh,
        const float* __restrict__ W_out, const float* __restrict__ b_out,
        float* __restrict__ ws, int N) {
    const int t = threadIdx.x;
    float* pb = ws + 2560;
    const int HH[6] = {0, 3, 6, 10, 13, 16};
    const int EH[6] = {0, 3, 6, 0, 3, 6};

    // per-channel BN scale/shift; channel ch = v*6 + c; flat f = c*210 + tt*7 + v
    if (t < 42) {
        const int v = t / 6, c = t % 6;
        float s = 0.f, q = 0.f;
        for (int tt = 0; tt < 30; ++tt) {
            const int f = c * 210 + tt * 7 + v;
            s += ws[f];
            q += ws[1280 + f];
        }
        const float cnt = 30.f * (float)N;
        const float mean = s / cnt;
        const float var = q / cnt - mean * mean;
        const float sc = bn_gamma[t] * rsqrtf(var + 1e-5f);
        pb[t] = sc;
        pb[64 + t] = bn_beta[t] - mean * sc;
    }
    // normalized adjacency: 6 GAT1 heads + GAT2 head0
    if (t >= 64 && t < 71) {
        const int idx = t - 64;
        const float* Bp = (idx < 6) ? (B1 + HH[idx] * 49) : B2;
        float* op = pb + 128 + idx * 49;
        float adj[49];
        for (int i = 0; i < 49; ++i) adj[i] = Bp[i];
        for (int i = 0; i < 7; ++i) adj[i * 8] += 1.f;
        float mn = adj[0], mx = adj[0];
        for (int i = 1; i < 49; ++i) { mn = fminf(mn, adj[i]); mx = fmaxf(mx, adj[i]); }
        const float inv = 1.f / (mx - mn);
        float rinv[7];
        for (int i = 0; i < 7; ++i) {
            float rs = 0.f;
            for (int j = 0; j < 7; ++j) { adj[i * 7 + j] = (adj[i * 7 + j] - mn) * inv; rs += adj[i * 7 + j]; }
            rinv[i] = rsqrtf(rs);
        }
        for (int i = 0; i < 7; ++i)
            for (int j = 0; j < 7; ++j)
                op[i * 7 + j] = adj[i * 7 + j] * rinv[i] * rinv[j];
    }
    // WB: fold a1 into W1 for the 6 live heads, repacked per-k
    for (int task = t; task < 6 * 180; task += 256) {
        const int hh = task / 180, k = task % 180;
        const int h = HH[hh];
        const float* Wp = W1 + ((size_t)h * 180 + k) * 9;
        float si = 0.f, sj = 0.f;
        for (int e = 0; e < 9; ++e) {
            const float w = Wp[e];
            si += w * a1[h * 18 + e];
            sj += w * a1[h * 18 + 9 + e];
        }
        pb[512 + k * 24 + hh * 3 + 0] = si;
        pb[512 + k * 24 + hh * 3 + 1] = sj;
        pb[512 + k * 24 + hh * 3 + 2] = Wp[EH[hh]];
    }
    // WA2 slots (replicated per c): head 0 of l2, f=0 column kept
    if (t < 30) {
        const float* Wp = W2 + t * 10;
        float si = 0.f, sj = 0.f;
        for (int f = 0; f < 10; ++f) {
            const float w = Wp[f];
            si += w * a2[f];
            sj += w * a2[10 + f];
        }
        for (int c = 0; c < 6; ++c) {
            const int k = c * 30 + t;
            pb[512 + k * 24 + 18] = si;
            pb[512 + k * 24 + 19] = sj;
            pb[512 + k * 24 + 20] = Wp[0];
        }
    }
    if (t < 84) pb[4832 + t] = b_ih[t] + b_hh[t];
    if (t < 147) pb[4928 + t] = W_out[t];
    if (t < 7) pb[5078 + t] = b_out[t];
}

// ---------------- kC: fused dots + attention + LSTM + out ----------------
// Single-wave blocks (64 threads, 8 samples). Phase 1 = r1-exact structure:
// per chunk, batch 30 gather loads into regs, then 660 FMAs (compiler already
// overlaps next chunk's loads; hand-pipelining measured -17% in r3).
// LDS trimmed to 14508 B -> 11 blocks/CU (was 14668 -> 10).
#define RS 252          // res row stride; 252%32=28 -> worst 2-way alias (free)
// LDS float map: res [8][252] @0, xs0 [8][84] @2016 (336B rows, 16B-aligned),
//   h2t [8][42] @2688, h1s [8][22] @3024, scsh [84] @3200, adjL [343] @3284
//   -> 3627 floats = 14508 B
__global__ __launch_bounds__(64) void kC_main(const float* __restrict__ x,
        const float* __restrict__ pb, const float* __restrict__ Wih,
        float* __restrict__ outp, int N) {
    __shared__ __align__(16) float sm[3627];
    float* res  = sm;
    float* xs0  = sm + 2016;
    float* h2t  = sm + 2688;
    float* h1s  = sm + 3024;
    float* scsh = sm + 3200;
    float* adjL = sm + 3284;

    const int t = threadIdx.x;
    const int n0 = blockIdx.x * 8;

    // ---- phase 0: params ----
    for (int i = t; i < 84; i += 64) scsh[i] = pb[i < 42 ? i : 22 + i];
    for (int i = t; i < 343; i += 64) adjL[i] = pb[128 + i];
    __syncthreads();

    // ---- phase 1: dots; thread = (v, nl), 56 active ----
    const int v = t >> 3, nl = t & 7;
    if (v < 7) {
        float s1[18];
#pragma unroll
        for (int i = 0; i < 18; ++i) s1[i] = 0.f;
        const float* xb = x + (size_t)(n0 + nl) * F1260 + v;
        const float* WB = pb + 512;
        for (int c = 0; c < 6; ++c) {
            const float sc = scsh[v * 6 + c];
            const float sh = scsh[42 + v * 6 + c];
            const float* xr = xb + c * 210;
            const float* wb = WB + (c * 30) * 24;
            float xv[30];
#pragma unroll
            for (int tt = 0; tt < 30; ++tt) xv[tt] = xr[tt * 7];   // batch loads
            float g0 = 0.f, g1 = 0.f, g2 = 0.f;
#pragma unroll
            for (int tt = 0; tt < 30; ++tt) {
                const float a = xv[tt] * sc + sh;
                const float* w = wb + tt * 24;                      // wave-uniform -> s_loads
#pragma unroll
                for (int q = 0; q < 18; ++q) s1[q] += a * w[q];
                g0 += a * w[18];
                g1 += a * w[19];
                g2 += a * w[20];
            }
            float* rp = res + nl * RS + 126 + (v * 6 + c) * 3;
            rp[0] = g0; rp[1] = g1; rp[2] = g2;
        }
#pragma unroll
        for (int q = 0; q < 18; ++q)
            res[nl * RS + v * 18 + q] = s1[q];
    }
    __syncthreads();

    // ---- phase 2: GAT1 heads; thread = (hh, nl), 48 active ----
    if (t < 48) {
        const int hh = t >> 3, nl2 = t & 7;
        float si[7], sj[7], we[7];
#pragma unroll
        for (int vv = 0; vv < 7; ++vv) {
            const float* rp = res + nl2 * RS + vv * 18 + hh * 3;
            si[vv] = rp[0]; sj[vv] = rp[1]; we[vv] = rp[2];
        }
        float mxsj = sj[0];
#pragma unroll
        for (int j = 1; j < 7; ++j) mxsj = fmaxf(mxsj, sj[j]);
        float p[7];
#pragma unroll
        for (int i = 0; i < 7; ++i) {
            const float m = leakyf(si[i] + mxsj);   // leaky monotonic -> row max
            float den = 0.f, num = 0.f;
#pragma unroll
            for (int j = 0; j < 7; ++j) {
                const float w = __expf(leakyf(si[i] + sj[j]) - m);
                den += w;
                num += w * we[j];
            }
            p[i] = num / den;
        }
        const float* An = adjL + hh * 49;
#pragma unroll
        for (int i = 0; i < 7; ++i) {
            float r = 0.f;
#pragma unroll
            for (int k = 0; k < 7; ++k) r += An[i * 7 + k] * p[k];
            xs0[nl2 * 84 + hh * 7 + i] = eluf(r);
        }
    }
    // ---- phase 2b: GAT2 softmax-over-channels; thread = (i, nl), 56 active ----
    if (t < 56) {
        const int i = t >> 3, nl2 = t & 7;
        float si2[6];
#pragma unroll
        for (int c = 0; c < 6; ++c)
            si2[c] = res[nl2 * RS + 126 + (i * 6 + c) * 3];
        float hc[6];
#pragma unroll
        for (int c = 0; c < 6; ++c) hc[c] = 0.f;
#pragma unroll
        for (int j = 0; j < 7; ++j) {
            float s[6];
            float m = -1e30f;
#pragma unroll
            for (int c = 0; c < 6; ++c) {
                const float* rp = res + nl2 * RS + 126 + (j * 6 + c) * 3;
                s[c] = leakyf(si2[c] + rp[1]);
                m = fmaxf(m, s[c]);
            }
            float den = 0.f;
#pragma unroll
            for (int c = 0; c < 6; ++c) { s[c] = __expf(s[c] - m); den += s[c]; }
            const float rd = 1.f / den;
#pragma unroll
            for (int c = 0; c < 6; ++c) {
                const float wh0 = res[nl2 * RS + 126 + (j * 6 + c) * 3 + 2];
                hc[c] += wh0 * s[c] * rd;
            }
        }
#pragma unroll
        for (int c = 0; c < 6; ++c)
            h2t[nl2 * 42 + i * 6 + c] = hc[c];
    }
    __syncthreads();

    // ---- phase 3: GAT2 adj multiply; thread = (c, nl), 48 active ----
    if (t < 48) {
        const int c = t >> 3, nl2 = t & 7;
        const float* An2 = adjL + 6 * 49;
        float h[7];
#pragma unroll
        for (int u = 0; u < 7; ++u) h[u] = h2t[nl2 * 42 + u * 6 + c];
#pragma unroll
        for (int vv = 0; vv < 7; ++vv) {
            float r = 0.f;
#pragma unroll
            for (int u = 0; u < 7; ++u) r += h[u] * An2[u * 7 + vv];
            xs0[nl2 * 84 + 42 + c * 7 + vv] = eluf(r);
        }
    }
    __syncthreads();

    // ---- phase 4: LSTM step 0; thread = (g8, nl), all 64; float4 reads ----
    {
        const int g8 = t >> 3, nl2 = t & 7;
        const float* bias = pb + 4832;
        const float4* xs4 = (const float4*)(xs0 + nl2 * 84);
        for (int gi = g8; gi < 21; gi += 8) {
            float ga = bias[gi], gg = bias[42 + gi], go = bias[63 + gi];
            const float4* wa = (const float4*)(Wih + gi * 84);
            const float4* wg = (const float4*)(Wih + (42 + gi) * 84);
            const float4* wo = (const float4*)(Wih + (63 + gi) * 84);
#pragma unroll
            for (int k = 0; k < 21; ++k) {
                const float4 xv = xs4[k];
                const float4 a4 = wa[k];
                const float4 g4 = wg[k];
                const float4 o4 = wo[k];
                ga += xv.x * a4.x + xv.y * a4.y + xv.z * a4.z + xv.w * a4.w;
                gg += xv.x * g4.x + xv.y * g4.y + xv.z * g4.z + xv.w * g4.w;
                go += xv.x * o4.x + xv.y * o4.y + xv.z * o4.z + xv.w * o4.w;
            }
            const float c1 = sigmoidf(ga) * tanh_fast(gg);
            h1s[nl2 * 22 + gi] = sigmoidf(go) * tanh_fast(c1);
        }
    }
    __syncthreads();

    // ---- phase 5: output projection; thread = nl*7+j, 56 active, coalesced ----
    if (t < 56) {
        const int nl2 = t / 7, j = t - nl2 * 7;
        const float* Wout = pb + 4928;
        float r = pb[5078 + j];
#pragma unroll
        for (int m = 0; m < 21; ++m) r += h1s[nl2 * 22 + m] * Wout[j * 21 + m];
        outp[(size_t)n0 * 7 + t] = r;
    }
}

extern "C" void kernel_launch(void* const* d_in, const int* in_sizes, int n_in,
                              void* d_out, int out_size, void* d_ws, size_t ws_size,
                              hipStream_t stream) {
    const int N = in_sizes[0] / F1260;

    const float* x        = (const float*)d_in[0];
    const float* bn_gamma = (const float*)d_in[1];
    const float* bn_beta  = (const float*)d_in[2];
    const float* W1       = (const float*)d_in[3];
    const float* a1       = (const float*)d_in[4];
    const float* B1       = (const float*)d_in[5];
    const float* W2       = (const float*)d_in[6];
    const float* a2       = (const float*)d_in[7];
    const float* B2       = (const float*)d_in[8];
    const float* W_ih     = (const float*)d_in[9];
    // d_in[10] = W_hh unused (h0 = 0 -> only LSTM step 0 matters)
    const float* b_ih     = (const float*)d_in[11];
    const float* b_hh     = (const float*)d_in[12];
    const float* W_out    = (const float*)d_in[13];
    const float* b_out    = (const float*)d_in[14];

    float* wsf = (float*)d_ws;

    hipMemsetAsync(d_ws, 0, 2560 * sizeof(float), stream);   // zero fsum/fsq

    kA_stats<<<dim3(N / 128), dim3(320), 0, stream>>>(x, wsf, N);
    kB_setup<<<dim3(1), dim3(256), 0, stream>>>(bn_gamma, bn_beta, W1, a1, B1,
                                                W2, a2, B2, b_ih, b_hh,
                                                W_out, b_out, wsf, N);
    kC_main<<<dim3(N / 8), dim3(64), 0, stream>>>(x, wsf + 2560, W_ih, (float*)d_out, N);
}

// Round 5
// 368.461 us; speedup vs baseline: 1.4782x; 1.0598x over previous
//
#include <hip/hip_runtime.h>

#define F1260 1260
#define NPART 128        // kA partial-blocks; partials = NPART*84 floats
#define PB_OFF 10752     // param block offset = NPART*84 rounded up to 128

__device__ __forceinline__ float leakyf(float x) { return x >= 0.f ? x : 0.2f * x; }
__device__ __forceinline__ float eluf(float x) { return x > 0.f ? x : expm1f(x); }
__device__ __forceinline__ float sigmoidf(float x) { return 1.f / (1.f + __expf(-x)); }
// fast tanh: exact saturation (exp->inf => 1, exp->0 => -1), ~1e-6 abs err
__device__ __forceinline__ float tanh_fast(float x) { return 1.f - 2.f / (__expf(2.f * x) + 1.f); }

// ws float layout (63.3 KB total; ws_size >= 103.7 KB verified in r2/r3):
//   0 .. NPART*84          : per-block channel partials (b*84 + ch = sum,
//                            b*84 + 42 + ch = sumsq), PLAIN STORES (no atomics)
//   param block pb = ws + PB_OFF:
//       pb+0    scale[42]      pb+64   shift[42]
//       pb+128  adjn[7][49]
//       pb+512  WB[180][24]  (per k=c*30+tt: [0..17]=GAT1 hh*3+{si,sj,we},
//                             [18..20]={a2si,a2sj,W2[tt][0]}, 3 pad)
//       pb+4832 bias[84] (b_ih+b_hh)   pb+4928 Wout[147]   pb+5078 bout[7]

// ---------------- kA: BN stats, float4-coalesced, NO GLOBAL ATOMICS ----------------
// r4 post-mortem: 645K device-scope atomicAdds over ~160 cache lines x 256
// contending blocks = cross-XCD line ping-pong + end-of-kernel drain ~ the
// persistent ~286 us "rest". Replaced by: per-block LDS reduce 1260 flat
// features -> 42 channel (sum,sq) pairs, 84 plain stores per block.
__global__ __launch_bounds__(320) void kA_stats(const float* __restrict__ x,
                                                float* __restrict__ ws, int rows) {
    __shared__ float fs[1260], fq[1260];
    const int t = threadIdx.x;
    const int n0 = blockIdx.x * rows;
    if (t < 315) {
        const int f0 = t * 4;
        float s0 = 0.f, s1 = 0.f, s2 = 0.f, s3 = 0.f;
        float q0 = 0.f, q1 = 0.f, q2 = 0.f, q3 = 0.f;
#pragma unroll 16
        for (int i = 0; i < rows; ++i) {
            const float4 a = *(const float4*)(x + (size_t)(n0 + i) * F1260 + f0);
            s0 += a.x; q0 += a.x * a.x;
            s1 += a.y; q1 += a.y * a.y;
            s2 += a.z; q2 += a.z * a.z;
            s3 += a.w; q3 += a.w * a.w;
        }
        fs[f0 + 0] = s0; fq[f0 + 0] = q0;
        fs[f0 + 1] = s1; fq[f0 + 1] = q1;
        fs[f0 + 2] = s2; fq[f0 + 2] = q2;
        fs[f0 + 3] = s3; fq[f0 + 3] = q3;
    }
    __syncthreads();
    // channel ch = v*6 + c aggregates flat f = c*210 + tt*7 + v over tt
    if (t < 42) {
        const int v = t / 6, c = t % 6;
        float s = 0.f, q = 0.f;
#pragma unroll
        for (int tt = 0; tt < 30; ++tt) {
            const int f = c * 210 + tt * 7 + v;
            s += fs[f];
            q += fq[f];
        }
        ws[blockIdx.x * 84 + t] = s;
        ws[blockIdx.x * 84 + 42 + t] = q;
    }
}

// ---------------- kB: finalize BN, adjacency norm, weight folds ----------------
__global__ __launch_bounds__(256) void kB_setup(
        const float* __restrict__ bn_gamma, const float* __restrict__ bn_beta,
        const float* __restrict__ W1, const float* __restrict__ a1, const float* __restrict__ B1,
        const float* __restrict__ W2, const float* __restrict__ a2, const float* __restrict__ B2,
        const float* __restrict__ b_ih, const float* __restrict__ b_hh,
        const float* __restrict__ W_out, const float* __restrict__ b_out,
        float* __restrict__ ws, int N) {
    const int t = threadIdx.x;
    float* pb = ws + PB_OFF;
    const int HH[6] = {0, 3, 6, 10, 13, 16};
    const int EH[6] = {0, 3, 6, 0, 3, 6};

    // per-channel BN scale/shift from NPART block partials
    if (t < 42) {
        float s = 0.f, q = 0.f;
        for (int b = 0; b < NPART; ++b) {
            s += ws[b * 84 + t];
            q += ws[b * 84 + 42 + t];
        }
        const float cnt = 30.f * (float)N;
        const float mean = s / cnt;
        const float var = q / cnt - mean * mean;
        const float sc = bn_gamma[t] * rsqrtf(var + 1e-5f);
        pb[t] = sc;
        pb[64 + t] = bn_beta[t] - mean * sc;
    }
    // normalized adjacency: 6 GAT1 heads + GAT2 head0
    if (t >= 64 && t < 71) {
        const int idx = t - 64;
        const float* Bp = (idx < 6) ? (B1 + HH[idx] * 49) : B2;
        float* op = pb + 128 + idx * 49;
        float adj[49];
        for (int i = 0; i < 49; ++i) adj[i] = Bp[i];
        for (int i = 0; i < 7; ++i) adj[i * 8] += 1.f;
        float mn = adj[0], mx = adj[0];
        for (int i = 1; i < 49; ++i) { mn = fminf(mn, adj[i]); mx = fmaxf(mx, adj[i]); }
        const float inv = 1.f / (mx - mn);
        float rinv[7];
        for (int i = 0; i < 7; ++i) {
            float rs = 0.f;
            for (int j = 0; j < 7; ++j) { adj[i * 7 + j] = (adj[i * 7 + j] - mn) * inv; rs += adj[i * 7 + j]; }
            rinv[i] = rsqrtf(rs);
        }
        for (int i = 0; i < 7; ++i)
            for (int j = 0; j < 7; ++j)
                op[i * 7 + j] = adj[i * 7 + j] * rinv[i] * rinv[j];
    }
    // WB: fold a1 into W1 for the 6 live heads, repacked per-k
    for (int task = t; task < 6 * 180; task += 256) {
        const int hh = task / 180, k = task % 180;
        const int h = HH[hh];
        const float* Wp = W1 + ((size_t)h * 180 + k) * 9;
        float si = 0.f, sj = 0.f;
        for (int e = 0; e < 9; ++e) {
            const float w = Wp[e];
            si += w * a1[h * 18 + e];
            sj += w * a1[h * 18 + 9 + e];
        }
        pb[512 + k * 24 + hh * 3 + 0] = si;
        pb[512 + k * 24 + hh * 3 + 1] = sj;
        pb[512 + k * 24 + hh * 3 + 2] = Wp[EH[hh]];
    }
    // WA2 slots (replicated per c): head 0 of l2, f=0 column kept
    if (t < 30) {
        const float* Wp = W2 + t * 10;
        float si = 0.f, sj = 0.f;
        for (int f = 0; f < 10; ++f) {
            const float w = Wp[f];
            si += w * a2[f];
            sj += w * a2[10 + f];
        }
        for (int c = 0; c < 6; ++c) {
            const int k = c * 30 + t;
            pb[512 + k * 24 + 18] = si;
            pb[512 + k * 24 + 19] = sj;
            pb[512 + k * 24 + 20] = Wp[0];
        }
    }
    if (t < 84) pb[4832 + t] = b_ih[t] + b_hh[t];
    if (t < 147) pb[4928 + t] = W_out[t];
    if (t < 7) pb[5078 + t] = b_out[t];
}

// ---------------- kC: fused dots + attention + LSTM + out ----------------
// r4-exact (measured 105 us). Single-wave blocks (64 threads, 8 samples);
// phase-1 batches 30 gather loads into regs then 660 FMAs per chunk (compiler
// schedules the overlap; hand-pipelining measured -17% in r3).
// LDS 14508 B -> 11 blocks/CU.
#define RS 252          // res row stride; 252%32=28 -> worst 2-way alias (free)
// LDS float map: res [8][252] @0, xs0 [8][84] @2016 (336B rows, 16B-aligned),
//   h2t [8][42] @2688, h1s [8][22] @3024, scsh [84] @3200, adjL [343] @3284
//   -> 3627 floats = 14508 B
__global__ __launch_bounds__(64) void kC_main(const float* __restrict__ x,
        const float* __restrict__ pb, const float* __restrict__ Wih,
        float* __restrict__ outp, int N) {
    __shared__ __align__(16) float sm[3627];
    float* res  = sm;
    float* xs0  = sm + 2016;
    float* h2t  = sm + 2688;
    float* h1s  = sm + 3024;
    float* scsh = sm + 3200;
    float* adjL = sm + 3284;

    const int t = threadIdx.x;
    const int n0 = blockIdx.x * 8;

    // ---- phase 0: params ----
    for (int i = t; i < 84; i += 64) scsh[i] = pb[i < 42 ? i : 22 + i];
    for (int i = t; i < 343; i += 64) adjL[i] = pb[128 + i];
    __syncthreads();

    // ---- phase 1: dots; thread = (v, nl), 56 active ----
    const int v = t >> 3, nl = t & 7;
    if (v < 7) {
        float s1[18];
#pragma unroll
        for (int i = 0; i < 18; ++i) s1[i] = 0.f;
        const float* xb = x + (size_t)(n0 + nl) * F1260 + v;
        const float* WB = pb + 512;
        for (int c = 0; c < 6; ++c) {
            const float sc = scsh[v * 6 + c];
            const float sh = scsh[42 + v * 6 + c];
            const float* xr = xb + c * 210;
            const float* wb = WB + (c * 30) * 24;
            float xv[30];
#pragma unroll
            for (int tt = 0; tt < 30; ++tt) xv[tt] = xr[tt * 7];   // batch loads
            float g0 = 0.f, g1 = 0.f, g2 = 0.f;
#pragma unroll
            for (int tt = 0; tt < 30; ++tt) {
                const float a = xv[tt] * sc + sh;
                const float* w = wb + tt * 24;                      // wave-uniform -> s_loads
#pragma unroll
                for (int q = 0; q < 18; ++q) s1[q] += a * w[q];
                g0 += a * w[18];
                g1 += a * w[19];
                g2 += a * w[20];
            }
            float* rp = res + nl * RS + 126 + (v * 6 + c) * 3;
            rp[0] = g0; rp[1] = g1; rp[2] = g2;
        }
#pragma unroll
        for (int q = 0; q < 18; ++q)
            res[nl * RS + v * 18 + q] = s1[q];
    }
    __syncthreads();

    // ---- phase 2: GAT1 heads; thread = (hh, nl), 48 active ----
    if (t < 48) {
        const int hh = t >> 3, nl2 = t & 7;
        float si[7], sj[7], we[7];
#pragma unroll
        for (int vv = 0; vv < 7; ++vv) {
            const float* rp = res + nl2 * RS + vv * 18 + hh * 3;
            si[vv] = rp[0]; sj[vv] = rp[1]; we[vv] = rp[2];
        }
        float mxsj = sj[0];
#pragma unroll
        for (int j = 1; j < 7; ++j) mxsj = fmaxf(mxsj, sj[j]);
        float p[7];
#pragma unroll
        for (int i = 0; i < 7; ++i) {
            const float m = leakyf(si[i] + mxsj);   // leaky monotonic -> row max
            float den = 0.f, num = 0.f;
#pragma unroll
            for (int j = 0; j < 7; ++j) {
                const float w = __expf(leakyf(si[i] + sj[j]) - m);
                den += w;
                num += w * we[j];
            }
            p[i] = num / den;
        }
        const float* An = adjL + hh * 49;
#pragma unroll
        for (int i = 0; i < 7; ++i) {
            float r = 0.f;
#pragma unroll
            for (int k = 0; k < 7; ++k) r += An[i * 7 + k] * p[k];
            xs0[nl2 * 84 + hh * 7 + i] = eluf(r);
        }
    }
    // ---- phase 2b: GAT2 softmax-over-channels; thread = (i, nl), 56 active ----
    if (t < 56) {
        const int i = t >> 3, nl2 = t & 7;
        float si2[6];
#pragma unroll
        for (int c = 0; c < 6; ++c)
            si2[c] = res[nl2 * RS + 126 + (i * 6 + c) * 3];
        float hc[6];
#pragma unroll
        for (int c = 0; c < 6; ++c) hc[c] = 0.f;
#pragma unroll
        for (int j = 0; j < 7; ++j) {
            float s[6];
            float m = -1e30f;
#pragma unroll
            for (int c = 0; c < 6; ++c) {
                const float* rp = res + nl2 * RS + 126 + (j * 6 + c) * 3;
                s[c] = leakyf(si2[c] + rp[1]);
                m = fmaxf(m, s[c]);
            }
            float den = 0.f;
#pragma unroll
            for (int c = 0; c < 6; ++c) { s[c] = __expf(s[c] - m); den += s[c]; }
            const float rd = 1.f / den;
#pragma unroll
            for (int c = 0; c < 6; ++c) {
                const float wh0 = res[nl2 * RS + 126 + (j * 6 + c) * 3 + 2];
                hc[c] += wh0 * s[c] * rd;
            }
        }
#pragma unroll
        for (int c = 0; c < 6; ++c)
            h2t[nl2 * 42 + i * 6 + c] = hc[c];
    }
    __syncthreads();

    // ---- phase 3: GAT2 adj multiply; thread = (c, nl), 48 active ----
    if (t < 48) {
        const int c = t >> 3, nl2 = t & 7;
        const float* An2 = adjL + 6 * 49;
        float h[7];
#pragma unroll
        for (int u = 0; u < 7; ++u) h[u] = h2t[nl2 * 42 + u * 6 + c];
#pragma unroll
        for (int vv = 0; vv < 7; ++vv) {
            float r = 0.f;
#pragma unroll
            for (int u = 0; u < 7; ++u) r += h[u] * An2[u * 7 + vv];
            xs0[nl2 * 84 + 42 + c * 7 + vv] = eluf(r);
        }
    }
    __syncthreads();

    // ---- phase 4: LSTM step 0; thread = (g8, nl), all 64; float4 reads ----
    {
        const int g8 = t >> 3, nl2 = t & 7;
        const float* bias = pb + 4832;
        const float4* xs4 = (const float4*)(xs0 + nl2 * 84);
        for (int gi = g8; gi < 21; gi += 8) {
            float ga = bias[gi], gg = bias[42 + gi], go = bias[63 + gi];
            const float4* wa = (const float4*)(Wih + gi * 84);
            const float4* wg = (const float4*)(Wih + (42 + gi) * 84);
            const float4* wo = (const float4*)(Wih + (63 + gi) * 84);
#pragma unroll
            for (int k = 0; k < 21; ++k) {
                const float4 xv = xs4[k];
                const float4 a4 = wa[k];
                const float4 g4 = wg[k];
                const float4 o4 = wo[k];
                ga += xv.x * a4.x + xv.y * a4.y + xv.z * a4.z + xv.w * a4.w;
                gg += xv.x * g4.x + xv.y * g4.y + xv.z * g4.z + xv.w * g4.w;
                go += xv.x * o4.x + xv.y * o4.y + xv.z * o4.z + xv.w * o4.w;
            }
            const float c1 = sigmoidf(ga) * tanh_fast(gg);
            h1s[nl2 * 22 + gi] = sigmoidf(go) * tanh_fast(c1);
        }
    }
    __syncthreads();

    // ---- phase 5: output projection; thread = nl*7+j, 56 active, coalesced ----
    if (t < 56) {
        const int nl2 = t / 7, j = t - nl2 * 7;
        const float* Wout = pb + 4928;
        float r = pb[5078 + j];
#pragma unroll
        for (int m = 0; m < 21; ++m) r += h1s[nl2 * 22 + m] * Wout[j * 21 + m];
        outp[(size_t)n0 * 7 + t] = r;
    }
}

extern "C" void kernel_launch(void* const* d_in, const int* in_sizes, int n_in,
                              void* d_out, int out_size, void* d_ws, size_t ws_size,
                              hipStream_t stream) {
    const int N = in_sizes[0] / F1260;

    const float* x        = (const float*)d_in[0];
    const float* bn_gamma = (const float*)d_in[1];
    const float* bn_beta  = (const float*)d_in[2];
    const float* W1       = (const float*)d_in[3];
    const float* a1       = (const float*)d_in[4];
    const float* B1       = (const float*)d_in[5];
    const float* W2       = (const float*)d_in[6];
    const float* a2       = (const float*)d_in[7];
    const float* B2       = (const float*)d_in[8];
    const float* W_ih     = (const float*)d_in[9];
    // d_in[10] = W_hh unused (h0 = 0 -> only LSTM step 0 matters)
    const float* b_ih     = (const float*)d_in[11];
    const float* b_hh     = (const float*)d_in[12];
    const float* W_out    = (const float*)d_in[13];
    const float* b_out    = (const float*)d_in[14];

    float* wsf = (float*)d_ws;

    // no memset needed: kA writes its partials with plain stores

    kA_stats<<<dim3(NPART), dim3(320), 0, stream>>>(x, wsf, N / NPART);
    kB_setup<<<dim3(1), dim3(256), 0, stream>>>(bn_gamma, bn_beta, W1, a1, B1,
                                                W2, a2, B2, b_ih, b_hh,
                                                W_out, b_out, wsf, N);
    kC_main<<<dim3(N / 8), dim3(64), 0, stream>>>(x, wsf + PB_OFF, W_ih, (float*)d_out, N);
}